// Round 1
// baseline (13432.312 us; speedup 1.0000x reference)
//
#include <hip/hip_runtime.h>

#define EPSV  1e-20f
#define BNEPS 1e-5f

// ---------------------------------------------------------------------------
// Weight prep: wn = |w| / (sum_{ci,k}|w| + EPS) per output filter co.
//   wB[ci][tap][co] = wn[co][ci][ky][kx]              (update conv, ic=ci, oc=co)
//   wA[co][tap'][ci] = wn[co][ci][2-ky][2-kx]         (ratio conv,  ic=co, oc=ci)
// Both in [IC][9][OC] layout for the conv kernel.
// ---------------------------------------------------------------------------
template<int CIN, int COUT>
__global__ __launch_bounds__(256) void prep_w_kernel(const float* __restrict__ w,
                                                     float* __restrict__ wA,
                                                     float* __restrict__ wB)
{
    const int co  = blockIdx.x;
    const int tid = threadIdx.x;
    const int N   = CIN * 9;
    const float* wrow = w + (size_t)co * N;

    float s = 0.f;
    for (int i = tid; i < N; i += 256) s += fabsf(wrow[i]);
    __shared__ float red[4];
    #pragma unroll
    for (int m = 32; m; m >>= 1) s += __shfl_xor(s, m, 64);
    if ((tid & 63) == 0) red[tid >> 6] = s;
    __syncthreads();
    s = red[0] + red[1] + red[2] + red[3];
    const float rn = 1.f / (s + EPSV);

    for (int i = tid; i < N; i += 256) {
        const int ci = i / 9, tap = i % 9;
        const int ky = tap / 3, kx = tap % 3;
        const float v = fabsf(wrow[i]) * rn;               // wn[co][ci][ky][kx]
        wB[((size_t)ci * 9 + tap) * COUT + co] = v;
        wA[((size_t)co * 9 + (2 - ky) * 3 + (2 - kx)) * CIN + ci] = v;
    }
}

// ---------------------------------------------------------------------------
// Input prep: xn = relu(x) / (sum_c relu(x) + EPS), per pixel.
// ---------------------------------------------------------------------------
template<int C>
__global__ __launch_bounds__(256) void xn_kernel(const float* __restrict__ in,
                                                 float* __restrict__ xn,
                                                 int npx, int HW)
{
    const int p = blockIdx.x * 256 + threadIdx.x;
    if (p >= npx) return;
    const int b = p / HW, r = p % HW;
    const float* ip = in + (size_t)b * C * HW + r;
    float*       op = xn + (size_t)b * C * HW + r;
    float s = 0.f;
    #pragma unroll 4
    for (int c = 0; c < C; ++c) s += fmaxf(ip[(size_t)c * HW], 0.f);
    const float rs = 1.f / (s + EPSV);
    #pragma unroll 4
    for (int c = 0; c < C; ++c) op[(size_t)c * HW] = fmaxf(ip[(size_t)c * HW], 0.f) * rs;
}

// h_u = 1 everywhere; S = sum over channels = COUT.
__global__ __launch_bounds__(256) void init_h_kernel(float* __restrict__ h, float* __restrict__ S,
                                                     int nh, int ns, float cval)
{
    const int i = blockIdx.x * 256 + threadIdx.x;
    if (i < nh) h[i] = 1.f;
    if (i < ns) S[i] = cval;
}

// ---------------------------------------------------------------------------
// 3x3 'same' conv, workgroup = TH x TW pixel tile x ALL output channels.
//   NORM_IN : divide staged input by (Sin+EPS) per pixel (ratio conv: input=h_u)
//   !UPDATE : out = aux / (acc + EPS)                      (ratio epilogue)
//   UPDATE  : out *= acc (h multiplicative update), and write per-pixel
//             channel sums to Sout.
// Weight layout: wgt[ic][9][OC], oc contiguous -> float4 loads.
// ---------------------------------------------------------------------------
template<int IC, int OC, int TH, int TW, int ICB, bool NORM_IN, bool UPDATE>
__global__ __launch_bounds__(256) void conv3_kernel(
    const float* __restrict__ in,    // [B,IC,H,W]
    const float* __restrict__ wgt,   // [IC][9][OC]
    const float* __restrict__ aux,   // ratio mode: xn [B,OC,H,W]
    float* __restrict__ out,         // ratio: [B,OC,H,W]; update: h inout
    const float* __restrict__ Sin,   // NORM_IN: per-pixel channel sums of `in`
    float* __restrict__ Sout,        // UPDATE: per-pixel channel sums of new h
    int H, int W)
{
    constexpr int PXL = TH * TW;        // 16 or 64 (pow2)
    constexpr int OCL = 256 / PXL;      // oc groups
    constexpr int NOC = (OC + OCL - 1) / OCL;
    constexpr int HS = TH + 2, WS = TW + 2, HALO = HS * WS;

    __shared__ float in_t[ICB * HALO];
    __shared__ float rS[NORM_IN ? HALO : 1];
    __shared__ float red[UPDATE ? 256 : 1];

    const int tid = threadIdx.x;
    const int px  = tid & (PXL - 1);
    const int ocg = tid / PXL;
    const int py  = px / TW, pxx = px % TW;
    const int x0 = blockIdx.x * TW, y0 = blockIdx.y * TH;
    const int b  = blockIdx.z;
    const int HW = H * W;

    if constexpr (NORM_IN) {
        for (int i = tid; i < HALO; i += 256) {
            const int yy = y0 + i / WS - 1, xx = x0 + i % WS - 1;
            float sv = 0.f;
            if (yy >= 0 && yy < H && xx >= 0 && xx < W)
                sv = Sin[(size_t)b * HW + yy * W + xx];
            rS[i] = 1.f / (sv + EPSV);
        }
    }

    float acc[NOC];
    #pragma unroll
    for (int j = 0; j < NOC; ++j) acc[j] = 0.f;

    for (int ic0 = 0; ic0 < IC; ic0 += ICB) {
        __syncthreads();
        for (int i = tid; i < ICB * HALO; i += 256) {
            const int ic = i / HALO, r = i - ic * HALO;
            const int yy = y0 + r / WS - 1, xx = x0 + r % WS - 1;
            float v = 0.f;
            if (yy >= 0 && yy < H && xx >= 0 && xx < W) {
                v = in[((size_t)(b * IC + ic0 + ic)) * HW + yy * W + xx];
                if constexpr (NORM_IN) v *= rS[r];
            }
            in_t[i] = v;
        }
        __syncthreads();
        for (int ic = 0; ic < ICB; ++ic) {
            const float* wr = wgt + ((size_t)(ic0 + ic) * 9) * OC + ocg * NOC;
            const float* it = in_t + ic * HALO + py * WS + pxx;
            #pragma unroll
            for (int t = 0; t < 9; ++t) {
                const float v = it[(t / 3) * WS + (t % 3)];
                if constexpr (NOC % 4 == 0) {
                    #pragma unroll
                    for (int q = 0; q < NOC / 4; ++q) {
                        const float4 wv = *reinterpret_cast<const float4*>(wr + t * OC + q * 4);
                        acc[4 * q + 0] = fmaf(v, wv.x, acc[4 * q + 0]);
                        acc[4 * q + 1] = fmaf(v, wv.y, acc[4 * q + 1]);
                        acc[4 * q + 2] = fmaf(v, wv.z, acc[4 * q + 2]);
                        acc[4 * q + 3] = fmaf(v, wv.w, acc[4 * q + 3]);
                    }
                } else {
                    #pragma unroll
                    for (int j = 0; j < NOC; ++j) {
                        if (ocg * NOC + j < OC)
                            acc[j] = fmaf(v, wr[t * OC + j], acc[j]);
                    }
                }
            }
        }
    }

    const int gy = y0 + py, gx = x0 + pxx;
    if constexpr (!UPDATE) {
        #pragma unroll
        for (int j = 0; j < NOC; ++j) {
            const int oc = ocg * NOC + j;
            if (oc < OC) {
                const size_t idx = ((size_t)(b * OC + oc)) * HW + gy * W + gx;
                out[idx] = aux[idx] / (acc[j] + EPSV);
            }
        }
    } else {
        float psum = 0.f;
        #pragma unroll
        for (int j = 0; j < NOC; ++j) {
            const int oc = ocg * NOC + j;
            const size_t idx = ((size_t)(b * OC + oc)) * HW + gy * W + gx;
            const float hn = out[idx] * acc[j];
            out[idx] = hn;
            psum += hn;
        }
        red[tid] = psum;
        __syncthreads();
        if (tid < PXL) {
            float s = 0.f;
            #pragma unroll
            for (int g = 0; g < OCL; ++g) s += red[g * PXL + tid];
            Sout[(size_t)b * HW + gy * W + gx] = s;   // tid==px here
        }
    }
}

// ---------------------------------------------------------------------------
// Post pass 1: y = relu(W1 . (h/S) + bias); per-workgroup partial (sum y, sum y^2)
// per channel, for deterministic BN stats. Tile = 8x4 pixels, all C channels.
// ---------------------------------------------------------------------------
template<int C>
__global__ __launch_bounds__(256) void post1_kernel(
    const float* __restrict__ h, const float* __restrict__ S,
    const float* __restrict__ w1, const float* __restrict__ bias,
    float* __restrict__ part, int H, int W)
{
    constexpr int NOC = C / 8;
    __shared__ float h_t[C * 32];
    __shared__ float sS[32];
    const int tid = threadIdx.x;
    const int px = tid & 31, ocg = tid >> 5;
    const int x0 = blockIdx.x * 8, y0 = blockIdx.y * 4, b = blockIdx.z;
    const int HW = H * W;

    if (tid < 32) {
        const int gy = y0 + (tid >> 3), gx = x0 + (tid & 7);
        sS[tid] = 1.f / (S[(size_t)b * HW + gy * W + gx] + EPSV);
    }
    __syncthreads();
    for (int i = tid; i < C * 32; i += 256) {
        const int c = i >> 5, p = i & 31;
        const int gy = y0 + (p >> 3), gx = x0 + (p & 7);
        h_t[i] = h[((size_t)(b * C + c)) * HW + gy * W + gx] * sS[p];
    }
    __syncthreads();

    const int wgid = (b * gridDim.y + blockIdx.y) * gridDim.x + blockIdx.x;
    for (int j = 0; j < NOC; ++j) {
        const int oc = ocg * NOC + j;
        const float* wrow = w1 + (size_t)oc * C;
        float a = 0.f;
        #pragma unroll 4
        for (int co = 0; co < C; ++co) a = fmaf(wrow[co], h_t[co * 32 + px], a);
        float y  = fmaxf(a + bias[oc], 0.f);
        float y2 = y * y;
        #pragma unroll
        for (int m = 16; m; m >>= 1) { y += __shfl_xor(y, m, 32); y2 += __shfl_xor(y2, m, 32); }
        if (px == 0) {
            part[((size_t)wgid * C + oc) * 2 + 0] = y;
            part[((size_t)wgid * C + oc) * 2 + 1] = y2;
        }
    }
}

// Reduce partials -> per-channel (scale, shift) for BN affine.
template<int C>
__global__ __launch_bounds__(256) void stats_kernel(const float* __restrict__ part, int nwg, float invM,
                                                    const float* __restrict__ gamma,
                                                    const float* __restrict__ beta,
                                                    float* __restrict__ stats)
{
    const int oc = blockIdx.x;
    const int tid = threadIdx.x;
    float s1 = 0.f, s2 = 0.f;
    for (int w = tid; w < nwg; w += 256) {
        s1 += part[((size_t)w * C + oc) * 2 + 0];
        s2 += part[((size_t)w * C + oc) * 2 + 1];
    }
    __shared__ float r1[4], r2[4];
    #pragma unroll
    for (int m = 32; m; m >>= 1) { s1 += __shfl_xor(s1, m, 64); s2 += __shfl_xor(s2, m, 64); }
    if ((tid & 63) == 0) { r1[tid >> 6] = s1; r2[tid >> 6] = s2; }
    __syncthreads();
    if (tid == 0) {
        s1 = r1[0] + r1[1] + r1[2] + r1[3];
        s2 = r2[0] + r2[1] + r2[2] + r2[3];
        const float mean = s1 * invM;
        const float var  = s2 * invM - mean * mean;
        const float rstd = rsqrtf(var + BNEPS);
        const float scale = gamma[oc] * rstd;
        stats[oc]     = scale;
        stats[C + oc] = beta[oc] - mean * scale;
    }
}

// Post pass 2: recompute y, apply BN affine, 2x2 avgpool, write block output.
template<int C>
__global__ __launch_bounds__(256) void post2_kernel(
    const float* __restrict__ h, const float* __restrict__ S,
    const float* __restrict__ w1, const float* __restrict__ bias,
    const float* __restrict__ stats, float* __restrict__ out, int H, int W)
{
    constexpr int NOC = C / 8;
    __shared__ float h_t[C * 32];
    __shared__ float sS[32];
    __shared__ float y_t[8 * 32];
    const int tid = threadIdx.x;
    const int px = tid & 31, ocg = tid >> 5;
    const int x0 = blockIdx.x * 8, y0 = blockIdx.y * 4, b = blockIdx.z;
    const int HW = H * W;

    if (tid < 32) {
        const int gy = y0 + (tid >> 3), gx = x0 + (tid & 7);
        sS[tid] = 1.f / (S[(size_t)b * HW + gy * W + gx] + EPSV);
    }
    __syncthreads();
    for (int i = tid; i < C * 32; i += 256) {
        const int c = i >> 5, p = i & 31;
        const int gy = y0 + (p >> 3), gx = x0 + (p & 7);
        h_t[i] = h[((size_t)(b * C + c)) * HW + gy * W + gx] * sS[p];
    }
    __syncthreads();

    const int Ho = H >> 1, Wo = W >> 1;
    for (int j = 0; j < NOC; ++j) {
        const int oc = ocg * NOC + j;
        const float* wrow = w1 + (size_t)oc * C;
        float a = 0.f;
        #pragma unroll 4
        for (int co = 0; co < C; ++co) a = fmaf(wrow[co], h_t[co * 32 + px], a);
        float y = fmaxf(a + bias[oc], 0.f);
        y = y * stats[oc] + stats[C + oc];
        y_t[ocg * 32 + px] = y;
        __syncthreads();
        if (tid < 64) {
            const int o8 = tid >> 3, pp = tid & 7;
            const int ppy = pp >> 2, ppx = pp & 3;
            const float* yr = y_t + o8 * 32 + ppy * 16 + ppx * 2;
            const float v = (yr[0] + yr[1] + yr[8] + yr[9]) * 0.25f;
            const int oco = o8 * NOC + j;
            out[((size_t)(b * C + oco)) * Ho * Wo + ((blockIdx.y << 1) + ppy) * Wo
                + (blockIdx.x << 2) + ppx] = v;
        }
        __syncthreads();
    }
}

// ---------------------------------------------------------------------------
// Per-block driver
// ---------------------------------------------------------------------------
template<int CIN, int COUT, int THr, int TWr, int ICBr, int ICBu>
static void launch_block(const float* pin,
                         const float* w_nnmf, const float* w1, const float* bias,
                         const float* gamma, const float* beta,
                         float* pout,
                         float* h, float* xn, float* ratio, float* S,
                         float* wA, float* wB, float* part, float* stats,
                         int H, int W, hipStream_t stream)
{
    const int B = 16, HW = H * W;
    prep_w_kernel<CIN, COUT><<<COUT, 256, 0, stream>>>(w_nnmf, wA, wB);
    const int npx = B * HW;
    xn_kernel<CIN><<<(npx + 255) / 256, 256, 0, stream>>>(pin, xn, npx, HW);
    const int nh = B * COUT * HW;
    init_h_kernel<<<(nh + 255) / 256, 256, 0, stream>>>(h, S, nh, npx, (float)COUT);
    for (int it = 0; it < 5; ++it) {
        // ratio = xn / (conv(h/S, wt) + EPS) : IC=COUT, OC=CIN
        conv3_kernel<COUT, CIN, THr, TWr, ICBr, true, false>
            <<<dim3(W / TWr, H / THr, B), 256, 0, stream>>>(h, wA, xn, ratio, S, nullptr, H, W);
        // h *= conv(ratio, wn); S = sum_c h : IC=CIN, OC=COUT
        conv3_kernel<CIN, COUT, 4, 4, ICBu, false, true>
            <<<dim3(W / 4, H / 4, B), 256, 0, stream>>>(ratio, wB, nullptr, h, nullptr, S, H, W);
    }
    dim3 pg(W / 8, H / 4, B);
    post1_kernel<COUT><<<pg, 256, 0, stream>>>(h, S, w1, bias, part, H, W);
    const int nwg = pg.x * pg.y * pg.z;
    stats_kernel<COUT><<<COUT, 256, 0, stream>>>(part, nwg, 1.0f / (float)(B * HW), gamma, beta, stats);
    post2_kernel<COUT><<<pg, 256, 0, stream>>>(h, S, w1, bias, stats, pout, H, W);
}

extern "C" void kernel_launch(void* const* d_in, const int* in_sizes, int n_in,
                              void* d_out, int out_size, void* d_ws, size_t ws_size,
                              hipStream_t stream)
{
    const float* x = (const float*)d_in[0];
    // Workspace layout (floats)
    float* ws    = (float*)d_ws;
    float* h     = ws;                    // 16*64*128*128 = 16,777,216
    float* xn    = h     + 16777216;      //  4,194,304
    float* ratio = xn    + 4194304;       //  4,194,304
    float* out0  = ratio + 4194304;       //  4,194,304  (block0 output)
    float* out1  = out0  + 4194304;       //  2,097,152  (block1 output)
    float* S     = out1  + 2097152;       //    262,144
    float* wA    = S     + 262144;        //    294,912
    float* wB    = wA    + 294912;        //    294,912
    float* part  = wB    + 294912;        //  1,048,576
    float* stats = part  + 1048576;       //        512
    // total ~33.4M floats ~= 127 MB

    // Block 0: Cin=3, Cout=64, 128x128 -> out0 [16,64,64,64]
    launch_block<3, 64, 8, 8, 16, 3>(
        x, (const float*)d_in[1], (const float*)d_in[2], (const float*)d_in[3],
        (const float*)d_in[4], (const float*)d_in[5],
        out0, h, xn, ratio, S, wA, wB, part, stats, 128, 128, stream);

    // Block 1: Cin=64, Cout=128, 64x64 -> out1 [16,128,32,32]
    launch_block<64, 128, 4, 4, 16, 16>(
        out0, (const float*)d_in[6], (const float*)d_in[7], (const float*)d_in[8],
        (const float*)d_in[9], (const float*)d_in[10],
        out1, h, xn, ratio, S, wA, wB, part, stats, 64, 64, stream);

    // Block 2: Cin=128, Cout=256, 32x32 -> d_out [16,256,16,16]
    launch_block<128, 256, 4, 4, 16, 16>(
        out1, (const float*)d_in[11], (const float*)d_in[12], (const float*)d_in[13],
        (const float*)d_in[14], (const float*)d_in[15],
        (float*)d_out, h, xn, ratio, S, wA, wB, part, stats, 32, 32, stream);
}

// Round 2
// 6355.854 us; speedup vs baseline: 2.1134x; 2.1134x over previous
//
#include <hip/hip_runtime.h>

#define EPSV  1e-20f
#define BNEPS 1e-5f

// ---------------------------------------------------------------------------
// Weight prep: wn = |w| / (sum_{ci,k}|w| + EPS) per output filter co.
//   wB[ci][tap][co] = wn[co][ci][ky][kx]              (update conv, ic=ci, oc=co)
//   wA[co][tap'][ci] = wn[co][ci][2-ky][2-kx]         (ratio conv,  ic=co, oc=ci)
// Both in [IC][9][OC] layout for the conv kernel.
// ---------------------------------------------------------------------------
template<int CIN, int COUT>
__global__ __launch_bounds__(256) void prep_w_kernel(const float* __restrict__ w,
                                                     float* __restrict__ wA,
                                                     float* __restrict__ wB)
{
    const int co  = blockIdx.x;
    const int tid = threadIdx.x;
    const int N   = CIN * 9;
    const float* wrow = w + (size_t)co * N;

    float s = 0.f;
    for (int i = tid; i < N; i += 256) s += fabsf(wrow[i]);
    __shared__ float red[4];
    #pragma unroll
    for (int m = 32; m; m >>= 1) s += __shfl_xor(s, m, 64);
    if ((tid & 63) == 0) red[tid >> 6] = s;
    __syncthreads();
    s = red[0] + red[1] + red[2] + red[3];
    const float rn = 1.f / (s + EPSV);

    for (int i = tid; i < N; i += 256) {
        const int ci = i / 9, tap = i % 9;
        const int ky = tap / 3, kx = tap % 3;
        const float v = fabsf(wrow[i]) * rn;               // wn[co][ci][ky][kx]
        wB[((size_t)ci * 9 + tap) * COUT + co] = v;
        wA[((size_t)co * 9 + (2 - ky) * 3 + (2 - kx)) * CIN + ci] = v;
    }
}

// ---------------------------------------------------------------------------
// Input prep: xn = relu(x) / (sum_c relu(x) + EPS), per pixel.
// ---------------------------------------------------------------------------
template<int C>
__global__ __launch_bounds__(256) void xn_kernel(const float* __restrict__ in,
                                                 float* __restrict__ xn,
                                                 int npx, int HW)
{
    const int p = blockIdx.x * 256 + threadIdx.x;
    if (p >= npx) return;
    const int b = p / HW, r = p % HW;
    const float* ip = in + (size_t)b * C * HW + r;
    float*       op = xn + (size_t)b * C * HW + r;
    float s = 0.f;
    #pragma unroll 4
    for (int c = 0; c < C; ++c) s += fmaxf(ip[(size_t)c * HW], 0.f);
    const float rs = 1.f / (s + EPSV);
    #pragma unroll 4
    for (int c = 0; c < C; ++c) op[(size_t)c * HW] = fmaxf(ip[(size_t)c * HW], 0.f) * rs;
}

// h_u = 1 everywhere; S = sum over channels = COUT.
__global__ __launch_bounds__(256) void init_h_kernel(float* __restrict__ h, float* __restrict__ S,
                                                     int nh, int ns, float cval)
{
    const int i = blockIdx.x * 256 + threadIdx.x;
    if (i < nh) h[i] = 1.f;
    if (i < ns) S[i] = cval;
}

// ---------------------------------------------------------------------------
// 3x3 'same' conv v2: register-tiled, pure LDS+FMA inner loop.
//   Workgroup = 256 threads = PXT pixel-slots x OCG oc-groups.
//   Thread computes NPX horizontally-contiguous pixels x NOC output channels.
//   Input halo tile AND weight chunk are cooperatively staged in LDS.
//   NORM_IN : divide staged input by (Sin+EPS) per pixel (ratio conv: input=h_u)
//   !UPDATE : out = aux / (acc + EPS)                      (ratio epilogue)
//   UPDATE  : out *= acc (h multiplicative update), Sout = per-pixel channel sum
// Weight layout in global: wgt[ic][9][OC], oc contiguous.
// ---------------------------------------------------------------------------
template<int IC, int OC, int TH, int TW, int PXT, int NPX, int NOC, int ICB,
         bool NORM_IN, bool UPDATE>
__global__ __launch_bounds__(256) void conv3v2_kernel(
    const float* __restrict__ in,    // [B,IC,H,W]
    const float* __restrict__ wgt,   // [IC][9][OC]
    const float* __restrict__ aux,   // ratio mode: xn [B,OC,H,W]
    float* __restrict__ out,         // ratio: [B,OC,H,W]; update: h inout
    const float* __restrict__ Sin,   // NORM_IN: per-pixel channel sums of `in`
    float* __restrict__ Sout,        // UPDATE: per-pixel channel sums of new h
    int H, int W)
{
    constexpr int OCG = 256 / PXT;          // oc groups
    constexpr int TPX = TH * TW;            // pixels per tile
    constexpr int SPR = TW / NPX;           // strips per tile row
    constexpr int HS  = TH + 2;
    constexpr int WSg = TW + 2;             // staged halo cols
    constexpr int WS  = ((WSg + 3) / 4) * 4; // padded stride (16B aligned rows)
    static_assert(TPX == PXT * NPX, "tile mismatch");
    static_assert(OCG * NOC >= OC, "oc coverage");
    static_assert(NPX == 4 || NPX == 2, "NPX");

    __shared__ float in_t[ICB * HS * WS];
    __shared__ float w_t[ICB * 9 * OC];
    __shared__ float rS[NORM_IN ? HS * WSg : 1];
    __shared__ float red[UPDATE ? OCG * TPX : 1];

    const int tid  = threadIdx.x;
    const int pxs  = tid % PXT;
    const int ocg  = tid / PXT;
    const int row  = pxs / SPR;
    const int col0 = (pxs % SPR) * NPX;
    const int x0 = blockIdx.x * TW, y0 = blockIdx.y * TH;
    const int b  = blockIdx.z;
    const int HW = H * W;

    if constexpr (NORM_IN) {
        for (int i = tid; i < HS * WSg; i += 256) {
            const int yy = y0 + i / WSg - 1, xx = x0 + i % WSg - 1;
            float sv = 0.f;
            if (yy >= 0 && yy < H && xx >= 0 && xx < W)
                sv = Sin[(size_t)b * HW + (size_t)yy * W + xx];
            rS[i] = 1.f / (sv + EPSV);
        }
    }

    float acc[NOC][NPX];
    #pragma unroll
    for (int j = 0; j < NOC; ++j)
        #pragma unroll
        for (int p = 0; p < NPX; ++p) acc[j][p] = 0.f;

    for (int ic0 = 0; ic0 < IC; ic0 += ICB) {
        __syncthreads();
        // ---- stage input halo (with optional per-pixel normalization) ----
        constexpr int NST = ICB * HS * WSg;
        for (int i = tid; i < NST; i += 256) {
            const int ic = i / (HS * WSg);
            const int r  = i % (HS * WSg);
            const int rr = r / WSg, cc = r % WSg;
            const int yy = y0 + rr - 1, xx = x0 + cc - 1;
            float v = 0.f;
            if (yy >= 0 && yy < H && xx >= 0 && xx < W) {
                v = in[((size_t)(b * IC + ic0 + ic)) * HW + (size_t)yy * W + xx];
                if constexpr (NORM_IN) v *= rS[r];
            }
            in_t[ic * (HS * WS) + rr * WS + cc] = v;
        }
        // ---- stage weight chunk (contiguous copy) ----
        if constexpr (OC % 4 == 0) {
            const float4* wsrc = reinterpret_cast<const float4*>(wgt + (size_t)ic0 * 9 * OC);
            float4* wdst = reinterpret_cast<float4*>(w_t);
            constexpr int NW4 = ICB * 9 * OC / 4;
            for (int i = tid; i < NW4; i += 256) wdst[i] = wsrc[i];
        } else {
            const float* wsrc = wgt + (size_t)ic0 * 9 * OC;
            constexpr int NW = ICB * 9 * OC;
            for (int i = tid; i < NW; i += 256) w_t[i] = wsrc[i];
        }
        __syncthreads();

        // ---- compute ----
        for (int ic = 0; ic < ICB; ++ic) {
            const float* wbase = w_t + ic * 9 * OC;
            const float* ibase = in_t + ic * (HS * WS) + row * WS + col0;

            float win[3][NPX + 2];
            #pragma unroll
            for (int dy = 0; dy < 3; ++dy) {
                const float* rp = ibase + dy * WS;
                if constexpr (NPX == 4) {
                    const float4 a = *reinterpret_cast<const float4*>(rp);
                    const float2 c = *reinterpret_cast<const float2*>(rp + 4);
                    win[dy][0] = a.x; win[dy][1] = a.y; win[dy][2] = a.z; win[dy][3] = a.w;
                    win[dy][4] = c.x; win[dy][5] = c.y;
                } else {
                    const float2 a = *reinterpret_cast<const float2*>(rp);
                    const float2 c = *reinterpret_cast<const float2*>(rp + 2);
                    win[dy][0] = a.x; win[dy][1] = a.y; win[dy][2] = c.x; win[dy][3] = c.y;
                }
            }

            #pragma unroll
            for (int t = 0; t < 9; ++t) {
                const int ky = t / 3, kx = t % 3;
                if constexpr (NOC % 4 == 0) {
                    #pragma unroll
                    for (int j4 = 0; j4 < NOC / 4; ++j4) {
                        const float4 wv = *reinterpret_cast<const float4*>(
                            wbase + t * OC + ocg * NOC + j4 * 4);
                        #pragma unroll
                        for (int p = 0; p < NPX; ++p) {
                            const float v = win[ky][kx + p];
                            acc[j4 * 4 + 0][p] = fmaf(v, wv.x, acc[j4 * 4 + 0][p]);
                            acc[j4 * 4 + 1][p] = fmaf(v, wv.y, acc[j4 * 4 + 1][p]);
                            acc[j4 * 4 + 2][p] = fmaf(v, wv.z, acc[j4 * 4 + 2][p]);
                            acc[j4 * 4 + 3][p] = fmaf(v, wv.w, acc[j4 * 4 + 3][p]);
                        }
                    }
                } else {
                    #pragma unroll
                    for (int j = 0; j < NOC; ++j) {
                        const int oc = ocg * NOC + j;
                        const float wv = (oc < OC) ? wbase[t * OC + oc] : 0.f;
                        #pragma unroll
                        for (int p = 0; p < NPX; ++p)
                            acc[j][p] = fmaf(win[ky][kx + p], wv, acc[j][p]);
                    }
                }
            }
        }
    }

    const int gy = y0 + row, gx0 = x0 + col0;

    if constexpr (!UPDATE) {
        #pragma unroll
        for (int j = 0; j < NOC; ++j) {
            const int oc = ocg * NOC + j;
            if constexpr (OCG * NOC > OC) { if (oc >= OC) continue; }
            const size_t idx = ((size_t)(b * OC + oc)) * HW + (size_t)gy * W + gx0;
            if constexpr (NPX == 4) {
                const float4 av = *reinterpret_cast<const float4*>(aux + idx);
                float4 ov;
                ov.x = av.x / (acc[j][0] + EPSV);
                ov.y = av.y / (acc[j][1] + EPSV);
                ov.z = av.z / (acc[j][2] + EPSV);
                ov.w = av.w / (acc[j][3] + EPSV);
                *reinterpret_cast<float4*>(out + idx) = ov;
            } else {
                const float2 av = *reinterpret_cast<const float2*>(aux + idx);
                float2 ov;
                ov.x = av.x / (acc[j][0] + EPSV);
                ov.y = av.y / (acc[j][1] + EPSV);
                *reinterpret_cast<float2*>(out + idx) = ov;
            }
        }
    } else {
        float psum[NPX];
        #pragma unroll
        for (int p = 0; p < NPX; ++p) psum[p] = 0.f;
        #pragma unroll
        for (int j = 0; j < NOC; ++j) {
            const int oc = ocg * NOC + j;
            if constexpr (OCG * NOC > OC) { if (oc >= OC) continue; }
            const size_t idx = ((size_t)(b * OC + oc)) * HW + (size_t)gy * W + gx0;
            if constexpr (NPX == 4) {
                float4 hv = *reinterpret_cast<const float4*>(out + idx);
                hv.x *= acc[j][0]; hv.y *= acc[j][1]; hv.z *= acc[j][2]; hv.w *= acc[j][3];
                psum[0] += hv.x; psum[1] += hv.y; psum[2] += hv.z; psum[3] += hv.w;
                *reinterpret_cast<float4*>(out + idx) = hv;
            } else {
                float2 hv = *reinterpret_cast<const float2*>(out + idx);
                hv.x *= acc[j][0]; hv.y *= acc[j][1];
                psum[0] += hv.x; psum[1] += hv.y;
                *reinterpret_cast<float2*>(out + idx) = hv;
            }
        }
        const int pix0 = row * TW + col0;
        #pragma unroll
        for (int p = 0; p < NPX; ++p) red[ocg * TPX + pix0 + p] = psum[p];
        __syncthreads();
        if (tid < TPX) {
            float s = 0.f;
            #pragma unroll
            for (int g = 0; g < OCG; ++g) s += red[g * TPX + tid];
            const int py = tid / TW, pxx = tid % TW;
            Sout[(size_t)b * HW + (size_t)(y0 + py) * W + (x0 + pxx)] = s;
        }
    }
}

// ---------------------------------------------------------------------------
// Post pass 1: y = relu(W1 . (h/S) + bias); per-workgroup partial (sum y, sum y^2)
// per channel, for deterministic BN stats. Tile = 8x4 pixels, all C channels.
// ---------------------------------------------------------------------------
template<int C>
__global__ __launch_bounds__(256) void post1_kernel(
    const float* __restrict__ h, const float* __restrict__ S,
    const float* __restrict__ w1, const float* __restrict__ bias,
    float* __restrict__ part, int H, int W)
{
    constexpr int NOC = C / 8;
    __shared__ float h_t[C * 32];
    __shared__ float sS[32];
    const int tid = threadIdx.x;
    const int px = tid & 31, ocg = tid >> 5;
    const int x0 = blockIdx.x * 8, y0 = blockIdx.y * 4, b = blockIdx.z;
    const int HW = H * W;

    if (tid < 32) {
        const int gy = y0 + (tid >> 3), gx = x0 + (tid & 7);
        sS[tid] = 1.f / (S[(size_t)b * HW + gy * W + gx] + EPSV);
    }
    __syncthreads();
    for (int i = tid; i < C * 32; i += 256) {
        const int c = i >> 5, p = i & 31;
        const int gy = y0 + (p >> 3), gx = x0 + (p & 7);
        h_t[i] = h[((size_t)(b * C + c)) * HW + gy * W + gx] * sS[p];
    }
    __syncthreads();

    const int wgid = (b * gridDim.y + blockIdx.y) * gridDim.x + blockIdx.x;
    for (int j = 0; j < NOC; ++j) {
        const int oc = ocg * NOC + j;
        const float* wrow = w1 + (size_t)oc * C;
        float a = 0.f;
        #pragma unroll 4
        for (int co = 0; co < C; ++co) a = fmaf(wrow[co], h_t[co * 32 + px], a);
        float y  = fmaxf(a + bias[oc], 0.f);
        float y2 = y * y;
        #pragma unroll
        for (int m = 16; m; m >>= 1) { y += __shfl_xor(y, m, 32); y2 += __shfl_xor(y2, m, 32); }
        if (px == 0) {
            part[((size_t)wgid * C + oc) * 2 + 0] = y;
            part[((size_t)wgid * C + oc) * 2 + 1] = y2;
        }
    }
}

// Reduce partials -> per-channel (scale, shift) for BN affine.
template<int C>
__global__ __launch_bounds__(256) void stats_kernel(const float* __restrict__ part, int nwg, float invM,
                                                    const float* __restrict__ gamma,
                                                    const float* __restrict__ beta,
                                                    float* __restrict__ stats)
{
    const int oc = blockIdx.x;
    const int tid = threadIdx.x;
    float s1 = 0.f, s2 = 0.f;
    for (int w = tid; w < nwg; w += 256) {
        s1 += part[((size_t)w * C + oc) * 2 + 0];
        s2 += part[((size_t)w * C + oc) * 2 + 1];
    }
    __shared__ float r1[4], r2[4];
    #pragma unroll
    for (int m = 32; m; m >>= 1) { s1 += __shfl_xor(s1, m, 64); s2 += __shfl_xor(s2, m, 64); }
    if ((tid & 63) == 0) { r1[tid >> 6] = s1; r2[tid >> 6] = s2; }
    __syncthreads();
    if (tid == 0) {
        s1 = r1[0] + r1[1] + r1[2] + r1[3];
        s2 = r2[0] + r2[1] + r2[2] + r2[3];
        const float mean = s1 * invM;
        const float var  = s2 * invM - mean * mean;
        const float rstd = rsqrtf(var + BNEPS);
        const float scale = gamma[oc] * rstd;
        stats[oc]     = scale;
        stats[C + oc] = beta[oc] - mean * scale;
    }
}

// Post pass 2: recompute y, apply BN affine, 2x2 avgpool, write block output.
template<int C>
__global__ __launch_bounds__(256) void post2_kernel(
    const float* __restrict__ h, const float* __restrict__ S,
    const float* __restrict__ w1, const float* __restrict__ bias,
    const float* __restrict__ stats, float* __restrict__ out, int H, int W)
{
    constexpr int NOC = C / 8;
    __shared__ float h_t[C * 32];
    __shared__ float sS[32];
    __shared__ float y_t[8 * 32];
    const int tid = threadIdx.x;
    const int px = tid & 31, ocg = tid >> 5;
    const int x0 = blockIdx.x * 8, y0 = blockIdx.y * 4, b = blockIdx.z;
    const int HW = H * W;

    if (tid < 32) {
        const int gy = y0 + (tid >> 3), gx = x0 + (tid & 7);
        sS[tid] = 1.f / (S[(size_t)b * HW + gy * W + gx] + EPSV);
    }
    __syncthreads();
    for (int i = tid; i < C * 32; i += 256) {
        const int c = i >> 5, p = i & 31;
        const int gy = y0 + (p >> 3), gx = x0 + (p & 7);
        h_t[i] = h[((size_t)(b * C + c)) * HW + gy * W + gx] * sS[p];
    }
    __syncthreads();

    const int Ho = H >> 1, Wo = W >> 1;
    for (int j = 0; j < NOC; ++j) {
        const int oc = ocg * NOC + j;
        const float* wrow = w1 + (size_t)oc * C;
        float a = 0.f;
        #pragma unroll 4
        for (int co = 0; co < C; ++co) a = fmaf(wrow[co], h_t[co * 32 + px], a);
        float y = fmaxf(a + bias[oc], 0.f);
        y = y * stats[oc] + stats[C + oc];
        y_t[ocg * 32 + px] = y;
        __syncthreads();
        if (tid < 64) {
            const int o8 = tid >> 3, pp = tid & 7;
            const int ppy = pp >> 2, ppx = pp & 3;
            const float* yr = y_t + o8 * 32 + ppy * 16 + ppx * 2;
            const float v = (yr[0] + yr[1] + yr[8] + yr[9]) * 0.25f;
            const int oco = o8 * NOC + j;
            out[((size_t)(b * C + oco)) * Ho * Wo + ((blockIdx.y << 1) + ppy) * Wo
                + (blockIdx.x << 2) + ppx] = v;
        }
        __syncthreads();
    }
}

// ---------------------------------------------------------------------------
// Per-block driver
// ---------------------------------------------------------------------------
template<int CIN, int COUT,
         int RTH, int RTW, int RPXT, int RNPX, int RNOC, int RICB,
         int UTH, int UTW, int UPXT, int UNPX, int UNOC, int UICB>
static void launch_block(const float* pin,
                         const float* w_nnmf, const float* w1, const float* bias,
                         const float* gamma, const float* beta,
                         float* pout,
                         float* h, float* xn, float* ratio, float* S,
                         float* wA, float* wB, float* part, float* stats,
                         int H, int W, hipStream_t stream)
{
    const int B = 16, HW = H * W;
    prep_w_kernel<CIN, COUT><<<COUT, 256, 0, stream>>>(w_nnmf, wA, wB);
    const int npx = B * HW;
    xn_kernel<CIN><<<(npx + 255) / 256, 256, 0, stream>>>(pin, xn, npx, HW);
    const int nh = B * COUT * HW;
    init_h_kernel<<<(nh + 255) / 256, 256, 0, stream>>>(h, S, nh, npx, (float)COUT);

    const dim3 rgrid(W / RTW, H / RTH, B);
    const dim3 ugrid(W / UTW, H / UTH, B);
    for (int it = 0; it < 5; ++it) {
        // ratio = xn / (conv(h/S, wt) + EPS) : IC=COUT, OC=CIN
        conv3v2_kernel<COUT, CIN, RTH, RTW, RPXT, RNPX, RNOC, RICB, true, false>
            <<<rgrid, 256, 0, stream>>>(h, wA, xn, ratio, S, nullptr, H, W);
        // h *= conv(ratio, wn); S = sum_c h : IC=CIN, OC=COUT
        conv3v2_kernel<CIN, COUT, UTH, UTW, UPXT, UNPX, UNOC, UICB, false, true>
            <<<ugrid, 256, 0, stream>>>(ratio, wB, nullptr, h, nullptr, S, H, W);
    }
    dim3 pg(W / 8, H / 4, B);
    post1_kernel<COUT><<<pg, 256, 0, stream>>>(h, S, w1, bias, part, H, W);
    const int nwg = pg.x * pg.y * pg.z;
    stats_kernel<COUT><<<COUT, 256, 0, stream>>>(part, nwg, 1.0f / (float)(B * HW), gamma, beta, stats);
    post2_kernel<COUT><<<pg, 256, 0, stream>>>(h, S, w1, bias, stats, pout, H, W);
}

extern "C" void kernel_launch(void* const* d_in, const int* in_sizes, int n_in,
                              void* d_out, int out_size, void* d_ws, size_t ws_size,
                              hipStream_t stream)
{
    const float* x = (const float*)d_in[0];
    // Workspace layout (floats)
    float* ws    = (float*)d_ws;
    float* h     = ws;                    // 16*64*128*128 = 16,777,216
    float* xn    = h     + 16777216;      //  4,194,304
    float* ratio = xn    + 4194304;       //  4,194,304
    float* out0  = ratio + 4194304;       //  4,194,304  (block0 output)
    float* out1  = out0  + 4194304;       //  2,097,152  (block1 output)
    float* S     = out1  + 2097152;       //    262,144
    float* wA    = S     + 262144;        //    294,912
    float* wB    = wA    + 294912;        //    294,912
    float* part  = wB    + 294912;        //  1,048,576
    float* stats = part  + 1048576;       //        512

    // Block 0: Cin=3, Cout=64, 128x128 -> out0 [16,64,64,64]
    // ratio: IC=64->OC=3  : tile 16x8, PXT=64, NPX=2, NOC=1, ICB=8  (grid 2048)
    // update: IC=3->OC=64 : tile 16x8, PXT=32, NPX=4, NOC=8, ICB=3  (grid 2048)
    launch_block<3, 64,
                 16, 8, 64, 2, 1, 8,
                 16, 8, 32, 4, 8, 3>(
        x, (const float*)d_in[1], (const float*)d_in[2], (const float*)d_in[3],
        (const float*)d_in[4], (const float*)d_in[5],
        out0, h, xn, ratio, S, wA, wB, part, stats, 128, 128, stream);

    // Block 1: Cin=64, Cout=128, 64x64 -> out1 [16,128,32,32]
    // ratio: IC=128->OC=64 : tile 16x8, PXT=32, NPX=4, NOC=8,  ICB=8 (grid 512)
    // update: IC=64->OC=128: tile 16x8, PXT=32, NPX=4, NOC=16, ICB=8 (grid 512)
    launch_block<64, 128,
                 16, 8, 32, 4, 8, 8,
                 16, 8, 32, 4, 16, 8>(
        out0, (const float*)d_in[6], (const float*)d_in[7], (const float*)d_in[8],
        (const float*)d_in[9], (const float*)d_in[10],
        out1, h, xn, ratio, S, wA, wB, part, stats, 64, 64, stream);

    // Block 2: Cin=128, Cout=256, 32x32 -> d_out [16,256,16,16]
    // ratio: IC=256->OC=128 : tile 4x8, PXT=8, NPX=4, NOC=4, ICB=8 (grid 512)
    // update: IC=128->OC=256: tile 4x8, PXT=8, NPX=4, NOC=8, ICB=4 (grid 512, LDS<64K)
    launch_block<128, 256,
                 4, 8, 8, 4, 4, 8,
                 4, 8, 8, 4, 8, 4>(
        out1, (const float*)d_in[11], (const float*)d_in[12], (const float*)d_in[13],
        (const float*)d_in[14], (const float*)d_in[15],
        (float*)d_out, h, xn, ratio, S, wA, wB, part, stats, 32, 32, stream);
}